// Round 3
// baseline (309.987 us; speedup 1.0000x reference)
//
#include <hip/hip_runtime.h>

#define LSZ   16
#define NBATCH 2
#define NSITE (NBATCH*LSZ*LSZ*LSZ*LSZ)   // 131072
#define NIN   10
#define NOUT  8
#define ND    4
#define NCPLX ((long)NSITE * NOUT * 9)   // 9,437,184 complex output elements
#define NLINE_PER_DIR (NSITE / LSZ)      // 8192
#define NLINK (NSITE * ND)               // 524288
#define WSTRIDE 108                      // u32 per site in LDS image: 9 e * 12 ch (10 used)

typedef unsigned int u32;

struct M3 { float re[9]; float im[9]; };

// bf16 pack helpers: u32 = bf16(lo) | bf16(hi)<<16
__device__ __forceinline__ unsigned short f2bf(float x) {
    u32 u = __float_as_uint(x);
    u32 r = (u + 0x7fffu + ((u >> 16) & 1u)) >> 16;   // RNE
    return (unsigned short)r;
}
__device__ __forceinline__ u32 packbf(float lo, float hi) {
    return (u32)f2bf(lo) | ((u32)f2bf(hi) << 16);
}

#if __has_builtin(__builtin_amdgcn_fdot2_f32_bf16)
#define CONV_DOT2 1
typedef __bf16 bf16x2 __attribute__((ext_vector_type(2)));
__device__ __forceinline__ bf16x2 as_b2(u32 v) {
    union { u32 u; bf16x2 b; } x; x.u = v; return x.b;
}
__device__ __forceinline__ void cdot(u32 w, u32 oa, u32 ob, float& sr, float& si) {
    sr = __builtin_amdgcn_fdot2_f32_bf16(as_b2(w), as_b2(oa), sr, false);
    si = __builtin_amdgcn_fdot2_f32_bf16(as_b2(w), as_b2(ob), si, false);
}
#else
#define CONV_DOT2 0
#endif

// o = a * b
__device__ __forceinline__ void mulM(M3& o, const M3& a, const M3& b) {
#pragma unroll
    for (int r = 0; r < 3; r++) {
#pragma unroll
        for (int c = 0; c < 3; c++) {
            float xr = 0.f, xi = 0.f;
#pragma unroll
            for (int k = 0; k < 3; k++) {
                float ar = a.re[r*3+k], ai = a.im[r*3+k];
                float br = b.re[k*3+c], bi = b.im[k*3+c];
                xr = fmaf(ar, br, xr); xr = fmaf(-ai, bi, xr);
                xi = fmaf(ar, bi, xi); xi = fmaf(ai, br, xi);
            }
            o.re[r*3+c] = xr; o.im[r*3+c] = xi;
        }
    }
}

// o = a * b^H
__device__ __forceinline__ void mulAdjM(M3& o, const M3& a, const M3& b) {
#pragma unroll
    for (int r = 0; r < 3; r++) {
#pragma unroll
        for (int c = 0; c < 3; c++) {
            float xr = 0.f, xi = 0.f;
#pragma unroll
            for (int k = 0; k < 3; k++) {
                float ar = a.re[r*3+k], ai = a.im[r*3+k];
                float br = b.re[c*3+k], bi = b.im[c*3+k];
                xr = fmaf(ar, br, xr); xr = fmaf(ai, bi, xr);
                xi = fmaf(ai, br, xi); xi = fmaf(-ar, bi, xi);
            }
            o.re[r*3+c] = xr; o.im[r*3+c] = xi;
        }
    }
}

// site s = b*65536 + x*4096 + y*256 + z*16 + t ; mu: 0->x,1->y,2->z,3->t
__device__ __forceinline__ int shift_site(int s, int mu, int k) {
    int sh = 12 - 4 * mu;
    int c  = (s >> sh) & 15;
    int nc = (c + k) & 15;
    return (s & ~(15 << sh)) | (nc << sh);
}

// ---------------- Kernel 1: Polyakov loops -> site-major T2 ------------------
// T2 layout: [site][mu][e] u32 (bf16 pair). Writes are scattered 36B chunks
// for mu<3 (producer-side scatter: stores don't stall), so that plaq's
// latency-critical gather is fully coalesced.
__global__ __launch_bounds__(256) void poly_kernel(const float* __restrict__ Ure,
                                                   const float* __restrict__ Uim,
                                                   u32* __restrict__ T2) {
    __shared__ float2 sm[16 * 145];   // 18.56 KB

    int line0 = blockIdx.x * 16;
    int mu    = line0 / NLINE_PER_DIR;
    int lidx0 = line0 - mu * NLINE_PER_DIR;
    int sh    = 12 - 4 * mu;
    int low0  = lidx0 & ((1 << sh) - 1);
    int high0 = lidx0 >> sh;
    int s_base0 = (high0 << (sh + 4)) | low0;

    for (int n = threadIdx.x; n < 16 * 16 * 9; n += 256) {
        int siteIdx = n / 9;
        int e       = n - siteIdx * 9;
        int site, l, c;
        if (mu == 3) { site = (lidx0 << 4) + siteIdx; l = siteIdx >> 4; c = siteIdx & 15; }
        else         { site = s_base0 + ((siteIdx >> 4) << sh) + (siteIdx & 15);
                       l = siteIdx & 15; c = siteIdx >> 4; }
        long g = ((long)site * 4 + mu) * 9 + e;
        sm[l * 145 + c * 9 + e] = make_float2(Ure[g], Uim[g]);
    }
    __syncthreads();

    int c = threadIdx.x & 15;
    int l = threadIdx.x >> 4;

    M3 P;
    {
        const float2* m0 = &sm[l * 145 + c * 9];
#pragma unroll
        for (int e = 0; e < 9; e++) { float2 v = m0[e]; P.re[e] = v.x; P.im[e] = v.y; }
    }
    for (int step = 1; step < LSZ; step++) {
        const float2* mn = &sm[l * 145 + ((c + step) & 15) * 9];
        M3 Un, Tm;
#pragma unroll
        for (int e = 0; e < 9; e++) { float2 v = mn[e]; Un.re[e] = v.x; Un.im[e] = v.y; }
        mulM(Tm, P, Un);
        P = Tm;
    }

    // site for (line=lidx0+l, start pos c): inverse of lidx decomposition
    int lidx = lidx0 + l;
    int low  = lidx & ((1 << sh) - 1);
    int high = lidx >> sh;
    int site = (high << (sh + 4)) | (c << sh) | low;
    u32* Tp = T2 + ((long)site * 4 + mu) * 9;
#pragma unroll
    for (int e = 0; e < 9; e++) Tp[e] = packbf(P.re[e], P.im[e]);
}

// ------- Kernel 2: plaquettes + merge-poly -> W planes -----------------------
// W layout: 27 planes of NSITE uint4. Plane p=(e*3+q); uint4 = j-slots 4q..4q+3
// (j=10,11 zero). Block writes 32 consecutive uint4 per plane -> coalesced.
// LDS: sU (37.9 KB) and sw (13.8 KB) are time-disjoint -> union them.
// T2 gather is site-major -> fully coalesced (was 4B/576B-stride scatter,
// ~16x line overfetch on the critical read path). U2 repack dropped: conv
// reads Ure/Uim directly (L3-resident), saving a 37.7 MB write here.
__global__ __launch_bounds__(192) void plaq_merge_kernel(const float* __restrict__ Ure,
                                                         const float* __restrict__ Uim,
                                                         const u32* __restrict__ T2,
                                                         u32* __restrict__ W) {
    __shared__ __align__(16) char smem[4 * 32 * 37 * sizeof(float2)];   // 37,888 B
    float2* sU = (float2*)smem;      // live: stage .. P compute
    u32*    sw = (u32*)smem;         // live: after barrier .. W4 write (13,824 B)

    int s0 = blockIdx.x * 32;

    for (int n = threadIdx.x; n < 8 * 16 * 36; n += 192) {
        int run = n / 576;
        int q   = n - run * 576;
        int sir = q / 36;
        int e36 = q - sir * 36;
        int slot = run >> 1, r = run & 1;
        int base = s0 + r * 16;
        if (slot < 3) base = shift_site(base, slot, 1);
        long g = (long)(base + sir) * 36 + e36;
        sU[(slot * 32 + r * 16 + sir) * 37 + e36] = make_float2(Ure[g], Uim[g]);
    }
    __syncthreads();

    int p  = threadIdx.x >> 5;
    int ls = threadIdx.x & 31;

    int mu = (p < 3) ? 0 : ((p < 5) ? 1 : 2);
    int nu = (mu == 0) ? (p + 1) : ((mu == 1) ? (p - 1) : 3);

    M3 Umu, Unu, Unu_f, Umu_f, T1, T2m, P;
    {
        const float2* pp;
#define LDM(m, slot, site, link) \
        pp = &sU[((slot) * 32 + (site)) * 37 + (link) * 9]; \
        _Pragma("unroll") \
        for (int e = 0; e < 9; e++) { float2 v = pp[e]; (m).re[e] = v.x; (m).im[e] = v.y; }

        LDM(Umu, 3, ls, mu);
        LDM(Unu, 3, ls, nu);
        LDM(Unu_f, mu, ls, nu);
        int lsrot = (ls & 16) | ((ls + 1) & 15);
        int fslot = (nu == 3) ? 3 : nu;
        int fsite = (nu == 3) ? lsrot : ls;
        LDM(Umu_f, fslot, fsite, mu);
#undef LDM
    }

    mulM(T1, Umu, Unu_f);
    mulAdjM(T2m, T1, Umu_f);
    mulAdjM(P, T2m, Unu);

    // all sU reads are done; reuse the LDS as sw
    __syncthreads();

#pragma unroll
    for (int e = 0; e < 9; e++) sw[ls * WSTRIDE + e * 12 + p] = packbf(P.re[e], P.im[e]);

    // pad j-slots 10,11 zeroed
    for (int it = threadIdx.x; it < 32 * 9 * 2; it += 192) {
        int site = it / 18;
        int r    = it - site * 18;
        sw[site * WSTRIDE + (r >> 1) * 12 + 10 + (r & 1)] = 0u;
    }

    // coalesced site-major T2 gather: 36 consecutive u32 per site
    for (int it = threadIdx.x; it < 32 * 36; it += 192) {
        int ls2 = it / 36;
        int r   = it - ls2 * 36;
        int mu2 = r / 9;
        int e2  = r - mu2 * 9;
        sw[ls2 * WSTRIDE + e2 * 12 + 6 + mu2] = T2[(long)(s0 + ls2) * 36 + r];
    }
    __syncthreads();

    // plane-transposed write: 27 planes x 32 consecutive uint4
    uint4* W4 = (uint4*)W;
    for (int it = threadIdx.x; it < 27 * 32; it += 192) {
        int pl  = it >> 5;
        int ls2 = it & 31;
        int e   = pl / 3, q = pl - e * 3;
        const uint4 v = *(const uint4*)(sw + ls2 * WSTRIDE + e * 12 + q * 4);
        W4[(long)pl * NSITE + s0 + ls2] = v;
    }
}

// ---------------- Kernel 3: gauge-equivariant conv (plane-W, i-paired) -------
// Wave = 16 consecutive-t sites x 4 lane-groups; lane group i0 handles output
// channels i0 and i0+4. Per (mu,kk): 27 plane loads of 16 consecutive uint4.
// Round-3 changes: 128-thread blocks (32 sites) to halve tail granularity
// (occupancy was stuck ~30% with 64-site blocks); som repacked j-innermost
// (ds_read_b128, +121 stride to spread banks); A read directly from Ure/Uim
// (U2 eliminated). NOTE: never cap VGPRs via launch_bounds min-waves > 3
// (round 1: forced 36 VGPR -> scratch spill -> 17x slower).
template <int MODE>
__global__ __launch_bounds__(128, 3) void conv_kernel(const float* __restrict__ Ure,
                                                      const float* __restrict__ Uim,
                                                      const u32* __restrict__ W,
                                                      const float* __restrict__ omre,
                                                      const float* __restrict__ omim,
                                                      float* __restrict__ out) {
    __shared__ __align__(16) char smraw[32 * 72 * sizeof(float)];   // 9,216 B
    uint2* som  = (uint2*)smraw;   // 8*121 uint2 = 7,744 B, live during loop
    float* sout = (float*)smraw;   // 9,216 B, live after loop (MODE 2)

    // som[(i)*121 + mk*10 + j] = (packbf(or,-oi), packbf(oi,or))
    for (int t = threadIdx.x; t < 8 * 12 * NIN; t += blockDim.x) {
        int i   = t / 120;
        int rem = t - i * 120;
        int mk  = rem / 10;
        int j   = rem - mk * 10;
        int mu = mk / 3, kk = mk - mu * 3;
        int oidx = ((i * NIN + j) * ND + mu) * 3 + kk;
        float orv = omre[oidx], oiv = omim[oidx];
        som[i * 121 + mk * 10 + j] = make_uint2(packbf(orv, -oiv), packbf(oiv, orv));
    }
    __syncthreads();

    // XCD-aware bijective swizzle (gridDim.x = 4096, divisible by 8)
    int chunk = gridDim.x >> 3;
    int lb    = ((int)blockIdx.x & 7) * chunk + ((int)blockIdx.x >> 3);

    int lane = threadIdx.x & 63;
    int wv   = threadIdx.x >> 6;          // 0..1
    int t    = lane & 15;                 // position in t-line
    int i0   = lane >> 4;                 // 0..3; handles i0, i0+4
    int s0b  = lb * 32;
    int sline = s0b + wv * 16;            // wave's t-line base (16-aligned)
    int s    = sline + t;

    const uint4* W4 = (const uint4*)W;

    float accr[2][9], acci[2][9];
#pragma unroll
    for (int p2 = 0; p2 < 2; p2++)
#pragma unroll
        for (int e = 0; e < 9; e++) { accr[p2][e] = 0.f; acci[p2][e] = 0.f; }

    for (int mu = 0; mu < ND; mu++) {
        float mr[2][9], mi[2][9];
#pragma unroll
        for (int p2 = 0; p2 < 2; p2++)
#pragma unroll
            for (int e = 0; e < 9; e++) { mr[p2][e] = 0.f; mi[p2][e] = 0.f; }

        for (int kk = 0; kk < 3; kk++) {
            int nb;
            if (mu < 3) nb = shift_site(s, mu, kk - 1);
            else        nb = sline + ((t + kk - 1) & 15);

            int mk = mu * 3 + kk;
            u32 oa0[NIN], ob0[NIN], oa1[NIN], ob1[NIN];
#pragma unroll
            for (int j = 0; j < NIN; j++) {
                uint2 v0 = som[i0 * 121 + mk * 10 + j];
                uint2 v1 = som[(i0 + 4) * 121 + mk * 10 + j];
                oa0[j] = v0.x; ob0[j] = v0.y;
                oa1[j] = v1.x; ob1[j] = v1.y;
            }

#pragma unroll
            for (int g = 0; g < 3; g++) {           // e-triple: 9 plane loads
                uint4 w[9];
#pragma unroll
                for (int q = 0; q < 9; q++) w[q] = W4[(long)(g * 9 + q) * NSITE + nb];
#pragma unroll
                for (int ee = 0; ee < 3; ee++) {
                    int e = g * 3 + ee;
                    uint4 a  = w[ee * 3 + 0];
                    uint4 b  = w[ee * 3 + 1];
                    uint4 cv = w[ee * 3 + 2];
                    float sr0 = mr[0][e], si0 = mi[0][e];
                    float sr1 = mr[1][e], si1 = mi[1][e];
#if CONV_DOT2
                    cdot(a.x,  oa0[0], ob0[0], sr0, si0); cdot(a.x,  oa1[0], ob1[0], sr1, si1);
                    cdot(a.y,  oa0[1], ob0[1], sr0, si0); cdot(a.y,  oa1[1], ob1[1], sr1, si1);
                    cdot(a.z,  oa0[2], ob0[2], sr0, si0); cdot(a.z,  oa1[2], ob1[2], sr1, si1);
                    cdot(a.w,  oa0[3], ob0[3], sr0, si0); cdot(a.w,  oa1[3], ob1[3], sr1, si1);
                    cdot(b.x,  oa0[4], ob0[4], sr0, si0); cdot(b.x,  oa1[4], ob1[4], sr1, si1);
                    cdot(b.y,  oa0[5], ob0[5], sr0, si0); cdot(b.y,  oa1[5], ob1[5], sr1, si1);
                    cdot(b.z,  oa0[6], ob0[6], sr0, si0); cdot(b.z,  oa1[6], ob1[6], sr1, si1);
                    cdot(b.w,  oa0[7], ob0[7], sr0, si0); cdot(b.w,  oa1[7], ob1[7], sr1, si1);
                    cdot(cv.x, oa0[8], ob0[8], sr0, si0); cdot(cv.x, oa1[8], ob1[8], sr1, si1);
                    cdot(cv.y, oa0[9], ob0[9], sr0, si0); cdot(cv.y, oa1[9], ob1[9], sr1, si1);
#else
                    u32 ws[NIN] = {a.x, a.y, a.z, a.w, b.x, b.y, b.z, b.w, cv.x, cv.y};
#pragma unroll
                    for (int j = 0; j < NIN; j++) {
                        float wr = __uint_as_float(ws[j] << 16);
                        float wi = __uint_as_float(ws[j] & 0xffff0000u);
                        float o0r = __uint_as_float(oa0[j] << 16), o0i = __uint_as_float(ob0[j] << 16);
                        float o1r = __uint_as_float(oa1[j] << 16), o1i = __uint_as_float(ob1[j] << 16);
                        float n0i = __uint_as_float(oa0[j] & 0xffff0000u);
                        float n1i = __uint_as_float(oa1[j] & 0xffff0000u);
                        float p0r = __uint_as_float(ob0[j] & 0xffff0000u);
                        float p1r = __uint_as_float(ob1[j] & 0xffff0000u);
                        sr0 = fmaf(o0r, wr, sr0); sr0 = fmaf(n0i, wi, sr0);
                        si0 = fmaf(o0i, wr, si0); si0 = fmaf(p0r, wi, si0);
                        sr1 = fmaf(o1r, wr, sr1); sr1 = fmaf(n1i, wi, sr1);
                        si1 = fmaf(o1i, wr, si1); si1 = fmaf(p1r, wi, si1);
                    }
#endif
                    mr[0][e] = sr0; mi[0][e] = si0;
                    mr[1][e] = sr1; mi[1][e] = si1;
                }
            }
        }

        // epilogue: out += A * Msum * A^H  (f32), for both i channels
        M3 A;
        {
            const float* pr = Ure + ((long)s * 4 + mu) * 9;
            const float* pi = Uim + ((long)s * 4 + mu) * 9;
#pragma unroll
            for (int e = 0; e < 9; e++) { A.re[e] = pr[e]; A.im[e] = pi[e]; }
        }
#pragma unroll
        for (int p2 = 0; p2 < 2; p2++) {
            M3 Tm;
#pragma unroll
            for (int r = 0; r < 3; r++) {
#pragma unroll
                for (int c = 0; c < 3; c++) {
                    float xr = 0.f, xi = 0.f;
#pragma unroll
                    for (int k = 0; k < 3; k++) {
                        float ar = A.re[r*3+k], ai = A.im[r*3+k];
                        float br = mr[p2][k*3+c], bi = mi[p2][k*3+c];
                        xr = fmaf(ar, br, xr); xr = fmaf(-ai, bi, xr);
                        xi = fmaf(ar, bi, xi); xi = fmaf(ai, br, xi);
                    }
                    Tm.re[r*3+c] = xr; Tm.im[r*3+c] = xi;
                }
            }
#pragma unroll
            for (int r = 0; r < 3; r++) {
#pragma unroll
                for (int c = 0; c < 3; c++) {
                    float xr = 0.f, xi = 0.f;
#pragma unroll
                    for (int k = 0; k < 3; k++) {
                        float ar = Tm.re[r*3+k], ai = Tm.im[r*3+k];
                        float br = A.re[c*3+k], bi = A.im[c*3+k];
                        xr = fmaf(ar, br, xr); xr = fmaf(ai, bi, xr);
                        if (MODE != 2) { xi = fmaf(ai, br, xi); xi = fmaf(-ar, bi, xi); }
                    }
                    accr[p2][r*3+c] += xr;
                    if (MODE != 2) acci[p2][r*3+c] += xi;
                }
            }
        }
    }

    if (MODE == 2) {
        // som is dead now; wait for all waves' loop reads before aliasing
        __syncthreads();
#pragma unroll
        for (int p2 = 0; p2 < 2; p2++) {
            int i = i0 + p2 * 4;
#pragma unroll
            for (int e = 0; e < 9; e++)
                sout[((wv * 16 + t) * 8 + i) * 9 + e] = accr[p2][e];
        }
        __syncthreads();
        long base = (long)lb * 2304;
        for (int n = threadIdx.x; n < 2304; n += 128) out[base + n] = sout[n];
    } else if (MODE == 0) {
#pragma unroll
        for (int p2 = 0; p2 < 2; p2++) {
            int i = i0 + p2 * 4;
            long cb = ((long)s * 8 + i) * 9;
            float2* op = (float2*)(out + cb * 2);
#pragma unroll
            for (int e = 0; e < 9; e++) op[e] = make_float2(accr[p2][e], acci[p2][e]);
        }
    } else {
#pragma unroll
        for (int p2 = 0; p2 < 2; p2++) {
            int i = i0 + p2 * 4;
            long cb = ((long)s * 8 + i) * 9;
#pragma unroll
            for (int e = 0; e < 9; e++) {
                out[cb + e]         = accr[p2][e];
                out[NCPLX + cb + e] = acci[p2][e];
            }
        }
    }
}

extern "C" void kernel_launch(void* const* d_in, const int* in_sizes, int n_in,
                              void* d_out, int out_size, void* d_ws, size_t ws_size,
                              hipStream_t stream) {
    const float* Ure  = (const float*)d_in[0];
    const float* Uim  = (const float*)d_in[1];
    const float* omre = (const float*)d_in[2];
    const float* omim = (const float*)d_in[3];
    float* out = (float*)d_out;

    const size_t wBytes = (size_t)NSITE * WSTRIDE * sizeof(u32);   // 56.6 MB (27 planes)
    if (ws_size < wBytes) return;

    u32* W  = (u32*)d_ws;
    u32* T2 = (u32*)d_out;   // 18.9 MB temp in d_out; overwritten by conv

    poly_kernel<<<NSITE * 4 / (16 * 16), 256, 0, stream>>>(Ure, Uim, T2);
    plaq_merge_kernel<<<NSITE / 32, 192, 0, stream>>>(Ure, Uim, T2, W);

    const int convGrid = NSITE / 32;   // 4096 blocks, 32 sites each
    if (out_size == (int)NCPLX)
        conv_kernel<2><<<convGrid, 128, 0, stream>>>(Ure, Uim, W, omre, omim, out);
    else if (out_size == (int)(2 * NCPLX))
        conv_kernel<1><<<convGrid, 128, 0, stream>>>(Ure, Uim, W, omre, omim, out);
    else
        conv_kernel<0><<<convGrid, 128, 0, stream>>>(Ure, Uim, W, omre, omim, out);
}

// Round 4
// 255.044 us; speedup vs baseline: 1.2154x; 1.2154x over previous
//
#include <hip/hip_runtime.h>

#define LSZ   16
#define NBATCH 2
#define NSITE (NBATCH*LSZ*LSZ*LSZ*LSZ)   // 131072
#define NIN   10
#define NOUT  8
#define ND    4
#define NCPLX ((long)NSITE * NOUT * 9)   // 9,437,184 complex output elements
#define NLINE_PER_DIR (NSITE / LSZ)      // 8192
#define NLINK (NSITE * ND)               // 524288
#define WSTRIDE 108                      // u32 per site in LDS image: 9 e * 12 ch (10 used)

typedef unsigned int u32;
typedef float  f32x4 __attribute__((ext_vector_type(4)));
typedef short  s16x8 __attribute__((ext_vector_type(8)));

struct M3 { float re[9]; float im[9]; };

// bf16 pack helpers: u32 = bf16(lo) | bf16(hi)<<16
__device__ __forceinline__ unsigned short f2bf(float x) {
    u32 u = __float_as_uint(x);
    u32 r = (u + 0x7fffu + ((u >> 16) & 1u)) >> 16;   // RNE
    return (unsigned short)r;
}
__device__ __forceinline__ u32 packbf(float lo, float hi) {
    return (u32)f2bf(lo) | ((u32)f2bf(hi) << 16);
}

__device__ __forceinline__ s16x8 as_s16x8(uint4 v) {
    union { uint4 u; s16x8 s; } x; x.u = v; return x.s;
}

// o = a * b
__device__ __forceinline__ void mulM(M3& o, const M3& a, const M3& b) {
#pragma unroll
    for (int r = 0; r < 3; r++) {
#pragma unroll
        for (int c = 0; c < 3; c++) {
            float xr = 0.f, xi = 0.f;
#pragma unroll
            for (int k = 0; k < 3; k++) {
                float ar = a.re[r*3+k], ai = a.im[r*3+k];
                float br = b.re[k*3+c], bi = b.im[k*3+c];
                xr = fmaf(ar, br, xr); xr = fmaf(-ai, bi, xr);
                xi = fmaf(ar, bi, xi); xi = fmaf(ai, br, xi);
            }
            o.re[r*3+c] = xr; o.im[r*3+c] = xi;
        }
    }
}

// o = a * b^H
__device__ __forceinline__ void mulAdjM(M3& o, const M3& a, const M3& b) {
#pragma unroll
    for (int r = 0; r < 3; r++) {
#pragma unroll
        for (int c = 0; c < 3; c++) {
            float xr = 0.f, xi = 0.f;
#pragma unroll
            for (int k = 0; k < 3; k++) {
                float ar = a.re[r*3+k], ai = a.im[r*3+k];
                float br = b.re[c*3+k], bi = b.im[c*3+k];
                xr = fmaf(ar, br, xr); xr = fmaf(ai, bi, xr);
                xi = fmaf(ai, br, xi); xi = fmaf(-ar, bi, xi);
            }
            o.re[r*3+c] = xr; o.im[r*3+c] = xi;
        }
    }
}

// site s = b*65536 + x*4096 + y*256 + z*16 + t ; mu: 0->x,1->y,2->z,3->t
__device__ __forceinline__ int shift_site(int s, int mu, int k) {
    int sh = 12 - 4 * mu;
    int c  = (s >> sh) & 15;
    int nc = (c + k) & 15;
    return (s & ~(15 << sh)) | (nc << sh);
}

// ---------------- Kernel 1: Polyakov loops -> site-major T2 ------------------
__global__ __launch_bounds__(256) void poly_kernel(const float* __restrict__ Ure,
                                                   const float* __restrict__ Uim,
                                                   u32* __restrict__ T2) {
    __shared__ float2 sm[16 * 145];   // 18.56 KB

    int line0 = blockIdx.x * 16;
    int mu    = line0 / NLINE_PER_DIR;
    int lidx0 = line0 - mu * NLINE_PER_DIR;
    int sh    = 12 - 4 * mu;
    int low0  = lidx0 & ((1 << sh) - 1);
    int high0 = lidx0 >> sh;
    int s_base0 = (high0 << (sh + 4)) | low0;

    for (int n = threadIdx.x; n < 16 * 16 * 9; n += 256) {
        int siteIdx = n / 9;
        int e       = n - siteIdx * 9;
        int site, l, c;
        if (mu == 3) { site = (lidx0 << 4) + siteIdx; l = siteIdx >> 4; c = siteIdx & 15; }
        else         { site = s_base0 + ((siteIdx >> 4) << sh) + (siteIdx & 15);
                       l = siteIdx & 15; c = siteIdx >> 4; }
        long g = ((long)site * 4 + mu) * 9 + e;
        sm[l * 145 + c * 9 + e] = make_float2(Ure[g], Uim[g]);
    }
    __syncthreads();

    int c = threadIdx.x & 15;
    int l = threadIdx.x >> 4;

    M3 P;
    {
        const float2* m0 = &sm[l * 145 + c * 9];
#pragma unroll
        for (int e = 0; e < 9; e++) { float2 v = m0[e]; P.re[e] = v.x; P.im[e] = v.y; }
    }
    for (int step = 1; step < LSZ; step++) {
        const float2* mn = &sm[l * 145 + ((c + step) & 15) * 9];
        M3 Un, Tm;
#pragma unroll
        for (int e = 0; e < 9; e++) { float2 v = mn[e]; Un.re[e] = v.x; Un.im[e] = v.y; }
        mulM(Tm, P, Un);
        P = Tm;
    }

    int lidx = lidx0 + l;
    int low  = lidx & ((1 << sh) - 1);
    int high = lidx >> sh;
    int site = (high << (sh + 4)) | (c << sh) | low;
    u32* Tp = T2 + ((long)site * 4 + mu) * 9;
#pragma unroll
    for (int e = 0; e < 9; e++) Tp[e] = packbf(P.re[e], P.im[e]);
}

// ------- Kernel 2: plaquettes + merge-poly -> W planes -----------------------
__global__ __launch_bounds__(192) void plaq_merge_kernel(const float* __restrict__ Ure,
                                                         const float* __restrict__ Uim,
                                                         const u32* __restrict__ T2,
                                                         u32* __restrict__ W) {
    __shared__ __align__(16) char smem[4 * 32 * 37 * sizeof(float2)];   // 37,888 B
    float2* sU = (float2*)smem;      // live: stage .. P compute
    u32*    sw = (u32*)smem;         // live: after barrier .. W4 write (13,824 B)

    int s0 = blockIdx.x * 32;

    for (int n = threadIdx.x; n < 8 * 16 * 36; n += 192) {
        int run = n / 576;
        int q   = n - run * 576;
        int sir = q / 36;
        int e36 = q - sir * 36;
        int slot = run >> 1, r = run & 1;
        int base = s0 + r * 16;
        if (slot < 3) base = shift_site(base, slot, 1);
        long g = (long)(base + sir) * 36 + e36;
        sU[(slot * 32 + r * 16 + sir) * 37 + e36] = make_float2(Ure[g], Uim[g]);
    }
    __syncthreads();

    int p  = threadIdx.x >> 5;
    int ls = threadIdx.x & 31;

    int mu = (p < 3) ? 0 : ((p < 5) ? 1 : 2);
    int nu = (mu == 0) ? (p + 1) : ((mu == 1) ? (p - 1) : 3);

    M3 Umu, Unu, Unu_f, Umu_f, T1, T2m, P;
    {
        const float2* pp;
#define LDM(m, slot, site, link) \
        pp = &sU[((slot) * 32 + (site)) * 37 + (link) * 9]; \
        _Pragma("unroll") \
        for (int e = 0; e < 9; e++) { float2 v = pp[e]; (m).re[e] = v.x; (m).im[e] = v.y; }

        LDM(Umu, 3, ls, mu);
        LDM(Unu, 3, ls, nu);
        LDM(Unu_f, mu, ls, nu);
        int lsrot = (ls & 16) | ((ls + 1) & 15);
        int fslot = (nu == 3) ? 3 : nu;
        int fsite = (nu == 3) ? lsrot : ls;
        LDM(Umu_f, fslot, fsite, mu);
#undef LDM
    }

    mulM(T1, Umu, Unu_f);
    mulAdjM(T2m, T1, Umu_f);
    mulAdjM(P, T2m, Unu);

    __syncthreads();   // all sU reads done; reuse LDS as sw

#pragma unroll
    for (int e = 0; e < 9; e++) sw[ls * WSTRIDE + e * 12 + p] = packbf(P.re[e], P.im[e]);

    for (int it = threadIdx.x; it < 32 * 9 * 2; it += 192) {
        int site = it / 18;
        int r    = it - site * 18;
        sw[site * WSTRIDE + (r >> 1) * 12 + 10 + (r & 1)] = 0u;
    }

    for (int it = threadIdx.x; it < 32 * 36; it += 192) {
        int ls2 = it / 36;
        int r   = it - ls2 * 36;
        int mu2 = r / 9;
        int e2  = r - mu2 * 9;
        sw[ls2 * WSTRIDE + e2 * 12 + 6 + mu2] = T2[(long)(s0 + ls2) * 36 + r];
    }
    __syncthreads();

    uint4* W4 = (uint4*)W;
    for (int it = threadIdx.x; it < 27 * 32; it += 192) {
        int pl  = it >> 5;
        int ls2 = it & 31;
        int e   = pl / 3, q = pl - e * 3;
        const uint4 v = *(const uint4*)(sw + ls2 * WSTRIDE + e * 12 + q * 4);
        W4[(long)pl * NSITE + s0 + ls2] = v;
    }
}

// ---------------- Kernel 3: MFMA gauge-equivariant conv ----------------------
// One wave per 16-site t-line. mfma_f32_16x16x32_bf16 per (mu,kk,e):
//   A[M=16 t-rows][K=32]: k=2j -> W_re[nb][e][j], k=2j+1 -> W_im. Lane l
//     (row=l&15, quad q=l>>4) holds k=q*8..q*8+7 = j-quad q -> ONE uint4 load
//     from plane e*3+q (q==3 -> zero frag; j>=10 already zero-padded in W).
//   B[K=32][N=16]: cols 0-7 Re-out (w_re,-w_im), cols 8-15 Im-out (w_im,w_re);
//     per-lane fragments precomputed into LDS (uint4 per (mk,lane)).
//   D (verified layout): lane holds col c=l&15 (channel-part), rows q*4+[0..3]
//     (t-sites). Epilogue per mu: shfl_xor(8) pairs re<->im lanes; lo lane
//     sandwiches sites q*4+{0,1}, hi lane q*4+{2,3}.
// Replaces 4320 v_dot2 + 324 loads per thread with 108 MFMA + 108 loads per
// wave. NOTE: never cap VGPRs via launch_bounds min-waves (round 1: 17x).
template <int MODE>
__global__ __launch_bounds__(256) void conv_kernel(const float* __restrict__ Ure,
                                                   const float* __restrict__ Uim,
                                                   const u32* __restrict__ W,
                                                   const float* __restrict__ omre,
                                                   const float* __restrict__ omim,
                                                   float* __restrict__ out) {
    __shared__ __align__(16) char smraw[64 * 72 * sizeof(float)];   // 18,432 B
    uint4* somB = (uint4*)smraw;   // [mk*64+lane], 12,288 B, live during loop
    float* sout = (float*)smraw;   // 18,432 B, live after loop (MODE 2)

    // B-fragment precompute: lane (c=lane&15, q=lane>>4); word w -> j=q*4+w
    for (int n = threadIdx.x; n < 12 * 64; n += 256) {
        int mk = n >> 6, ln = n & 63;
        int q = ln >> 4, c = ln & 15, i = c & 7;
        int mu = mk / 3, kk = mk - mu * 3;
        u32 wv[4];
#pragma unroll
        for (int w = 0; w < 4; w++) {
            int j = q * 4 + w;
            u32 val = 0u;
            if (q < 3 && j < NIN) {
                int oidx = ((i * NIN + j) * ND + mu) * 3 + kk;
                float orv = omre[oidx], oiv = omim[oidx];
                val = (c < 8) ? packbf(orv, -oiv) : packbf(oiv, orv);
            }
            wv[w] = val;
        }
        somB[n] = make_uint4(wv[0], wv[1], wv[2], wv[3]);
    }
    __syncthreads();

    // XCD-aware bijective swizzle (gridDim.x = 2048, divisible by 8)
    int chunk = gridDim.x >> 3;
    int lb    = ((int)blockIdx.x & 7) * chunk + ((int)blockIdx.x >> 3);

    int lane = threadIdx.x & 63;
    int wv_  = threadIdx.x >> 6;          // 0..3
    int r    = lane & 15;                 // A-row (t) / D-col (channel-part)
    int q    = lane >> 4;                 // k-quad / D-row block
    int s0b  = lb * 64;
    int sline = s0b + wv_ * 16;

    const uint4* W4 = (const uint4*)W;

    bool hi = (r >= 8);
    int  i  = r & 7;                      // output channel for epilogue
    int  reg0 = hi ? 2 : 0;               // D-rows handled by this lane

    float accr[2][9], acci[2][9];
#pragma unroll
    for (int rr = 0; rr < 2; rr++)
#pragma unroll
        for (int e = 0; e < 9; e++) { accr[rr][e] = 0.f; acci[rr][e] = 0.f; }

    for (int mu = 0; mu < ND; mu++) {
        f32x4 acc[9];
#pragma unroll
        for (int e = 0; e < 9; e++) acc[e] = (f32x4)(0.f);

        for (int kk = 0; kk < 3; kk++) {
            int mk = mu * 3 + kk;
            s16x8 bfrag = as_s16x8(somB[mk * 64 + lane]);

            int nb;
            if (mu < 3) nb = shift_site(sline, mu, kk - 1) + r;
            else        nb = sline + ((r + kk - 1) & 15);

            uint4 w9[9];
            if (q < 3) {
#pragma unroll
                for (int e = 0; e < 9; e++) w9[e] = W4[(long)(e * 3 + q) * NSITE + nb];
            } else {
#pragma unroll
                for (int e = 0; e < 9; e++) w9[e] = make_uint4(0u, 0u, 0u, 0u);
            }
#pragma unroll
            for (int e = 0; e < 9; e++)
                acc[e] = __builtin_amdgcn_mfma_f32_16x16x32_bf16(as_s16x8(w9[e]), bfrag, acc[e], 0, 0, 0);
        }

        // exchange: partner holds the other complex part of M for my 2 rows
        float own[2][9], oth[2][9];
#pragma unroll
        for (int e = 0; e < 9; e++) {
            float t0 = __shfl_xor(acc[e][0], 8);
            float t1 = __shfl_xor(acc[e][1], 8);
            float t2 = __shfl_xor(acc[e][2], 8);
            float t3 = __shfl_xor(acc[e][3], 8);
            own[0][e] = hi ? acc[e][2] : acc[e][0];
            own[1][e] = hi ? acc[e][3] : acc[e][1];
            oth[0][e] = hi ? t2 : t0;
            oth[1][e] = hi ? t3 : t1;
        }

        // sandwich A * M * A^H for this lane's 2 sites
#pragma unroll
        for (int rr = 0; rr < 2; rr++) {
            int site = sline + q * 4 + reg0 + rr;
            M3 A, M;
            {
                const float* pr = Ure + ((long)site * 4 + mu) * 9;
                const float* pi = Uim + ((long)site * 4 + mu) * 9;
#pragma unroll
                for (int e = 0; e < 9; e++) { A.re[e] = pr[e]; A.im[e] = pi[e]; }
            }
#pragma unroll
            for (int e = 0; e < 9; e++) {
                M.re[e] = hi ? oth[rr][e] : own[rr][e];
                M.im[e] = hi ? own[rr][e] : oth[rr][e];
            }
            M3 Tm;
#pragma unroll
            for (int rw = 0; rw < 3; rw++) {
#pragma unroll
                for (int cl = 0; cl < 3; cl++) {
                    float xr = 0.f, xi = 0.f;
#pragma unroll
                    for (int k = 0; k < 3; k++) {
                        float ar = A.re[rw*3+k], ai = A.im[rw*3+k];
                        float br = M.re[k*3+cl], bi = M.im[k*3+cl];
                        xr = fmaf(ar, br, xr); xr = fmaf(-ai, bi, xr);
                        xi = fmaf(ar, bi, xi); xi = fmaf(ai, br, xi);
                    }
                    Tm.re[rw*3+cl] = xr; Tm.im[rw*3+cl] = xi;
                }
            }
#pragma unroll
            for (int rw = 0; rw < 3; rw++) {
#pragma unroll
                for (int cl = 0; cl < 3; cl++) {
                    float xr = 0.f, xi = 0.f;
#pragma unroll
                    for (int k = 0; k < 3; k++) {
                        float ar = Tm.re[rw*3+k], ai = Tm.im[rw*3+k];
                        float br = A.re[cl*3+k], bi = A.im[cl*3+k];
                        xr = fmaf(ar, br, xr); xr = fmaf(ai, bi, xr);
                        if (MODE != 2) { xi = fmaf(ai, br, xi); xi = fmaf(-ar, bi, xi); }
                    }
                    accr[rr][rw*3+cl] += xr;
                    if (MODE != 2) acci[rr][rw*3+cl] += xi;
                }
            }
        }
    }

    if (MODE == 2) {
        __syncthreads();   // all somB reads done before aliasing as sout
#pragma unroll
        for (int rr = 0; rr < 2; rr++) {
            int tloc = wv_ * 16 + q * 4 + reg0 + rr;
#pragma unroll
            for (int e = 0; e < 9; e++)
                sout[(tloc * 8 + i) * 9 + e] = accr[rr][e];
        }
        __syncthreads();
        long base = (long)lb * 4608;
        for (int n = threadIdx.x; n < 4608; n += 256) out[base + n] = sout[n];
    } else if (MODE == 0) {
#pragma unroll
        for (int rr = 0; rr < 2; rr++) {
            int site = sline + q * 4 + reg0 + rr;
            long cb = ((long)site * 8 + i) * 9;
            float2* op = (float2*)(out + cb * 2);
#pragma unroll
            for (int e = 0; e < 9; e++) op[e] = make_float2(accr[rr][e], acci[rr][e]);
        }
    } else {
#pragma unroll
        for (int rr = 0; rr < 2; rr++) {
            int site = sline + q * 4 + reg0 + rr;
            long cb = ((long)site * 8 + i) * 9;
#pragma unroll
            for (int e = 0; e < 9; e++) {
                out[cb + e]         = accr[rr][e];
                out[NCPLX + cb + e] = acci[rr][e];
            }
        }
    }
}

extern "C" void kernel_launch(void* const* d_in, const int* in_sizes, int n_in,
                              void* d_out, int out_size, void* d_ws, size_t ws_size,
                              hipStream_t stream) {
    const float* Ure  = (const float*)d_in[0];
    const float* Uim  = (const float*)d_in[1];
    const float* omre = (const float*)d_in[2];
    const float* omim = (const float*)d_in[3];
    float* out = (float*)d_out;

    const size_t wBytes = (size_t)NSITE * WSTRIDE * sizeof(u32);   // 56.6 MB (27 planes)
    if (ws_size < wBytes) return;

    u32* W  = (u32*)d_ws;
    u32* T2 = (u32*)d_out;   // 18.9 MB temp in d_out; overwritten by conv

    poly_kernel<<<NSITE * 4 / (16 * 16), 256, 0, stream>>>(Ure, Uim, T2);
    plaq_merge_kernel<<<NSITE / 32, 192, 0, stream>>>(Ure, Uim, T2, W);

    const int convGrid = NSITE / 64;   // 2048 blocks, 64 sites each (4 waves)
    if (out_size == (int)NCPLX)
        conv_kernel<2><<<convGrid, 256, 0, stream>>>(Ure, Uim, W, omre, omim, out);
    else if (out_size == (int)(2 * NCPLX))
        conv_kernel<1><<<convGrid, 256, 0, stream>>>(Ure, Uim, W, omre, omim, out);
    else
        conv_kernel<0><<<convGrid, 256, 0, stream>>>(Ure, Uim, W, omre, omim, out);
}

// Round 5
// 239.815 us; speedup vs baseline: 1.2926x; 1.0635x over previous
//
#include <hip/hip_runtime.h>

#define LSZ   16
#define NBATCH 2
#define NSITE (NBATCH*LSZ*LSZ*LSZ*LSZ)   // 131072
#define NIN   10
#define NOUT  8
#define ND    4
#define NCPLX ((long)NSITE * NOUT * 9)   // 9,437,184 complex output elements
#define NLINE_PER_DIR (NSITE / LSZ)      // 8192
#define NLINK (NSITE * ND)               // 524288
#define WSTRIDE 108                      // u32 per site in LDS image: 9 e * 12 ch (10 used)

typedef unsigned int u32;
typedef float  f32x4 __attribute__((ext_vector_type(4)));
typedef short  s16x8 __attribute__((ext_vector_type(8)));

struct M3 { float re[9]; float im[9]; };

// bf16 pack helpers: u32 = bf16(lo) | bf16(hi)<<16
__device__ __forceinline__ unsigned short f2bf(float x) {
    u32 u = __float_as_uint(x);
    u32 r = (u + 0x7fffu + ((u >> 16) & 1u)) >> 16;   // RNE
    return (unsigned short)r;
}
__device__ __forceinline__ u32 packbf(float lo, float hi) {
    return (u32)f2bf(lo) | ((u32)f2bf(hi) << 16);
}

__device__ __forceinline__ s16x8 as_s16x8(uint4 v) {
    union { uint4 u; s16x8 s; } x; x.u = v; return x.s;
}

// o = a * b
__device__ __forceinline__ void mulM(M3& o, const M3& a, const M3& b) {
#pragma unroll
    for (int r = 0; r < 3; r++) {
#pragma unroll
        for (int c = 0; c < 3; c++) {
            float xr = 0.f, xi = 0.f;
#pragma unroll
            for (int k = 0; k < 3; k++) {
                float ar = a.re[r*3+k], ai = a.im[r*3+k];
                float br = b.re[k*3+c], bi = b.im[k*3+c];
                xr = fmaf(ar, br, xr); xr = fmaf(-ai, bi, xr);
                xi = fmaf(ar, bi, xi); xi = fmaf(ai, br, xi);
            }
            o.re[r*3+c] = xr; o.im[r*3+c] = xi;
        }
    }
}

// o = a * b^H
__device__ __forceinline__ void mulAdjM(M3& o, const M3& a, const M3& b) {
#pragma unroll
    for (int r = 0; r < 3; r++) {
#pragma unroll
        for (int c = 0; c < 3; c++) {
            float xr = 0.f, xi = 0.f;
#pragma unroll
            for (int k = 0; k < 3; k++) {
                float ar = a.re[r*3+k], ai = a.im[r*3+k];
                float br = b.re[c*3+k], bi = b.im[c*3+k];
                xr = fmaf(ar, br, xr); xr = fmaf(ai, bi, xr);
                xi = fmaf(ai, br, xi); xi = fmaf(-ar, bi, xi);
            }
            o.re[r*3+c] = xr; o.im[r*3+c] = xi;
        }
    }
}

// site s = b*65536 + x*4096 + y*256 + z*16 + t ; mu: 0->x,1->y,2->z,3->t
__device__ __forceinline__ int shift_site(int s, int mu, int k) {
    int sh = 12 - 4 * mu;
    int c  = (s >> sh) & 15;
    int nc = (c + k) & 15;
    return (s & ~(15 << sh)) | (nc << sh);
}

// ---------------- Kernel 1: Polyakov via parallel doubling scan --------------
// One thread per (line, start-pos c). The 16 start positions of a line live in
// one 16-lane group, so the scan exchanges are pure __shfl (no LDS/barrier).
// M2(c)=U_c*U_{c+1}; M4(c)=M2(c)*M2(c+2); M8; M16(c)=P_c (cyclic mod 16).
// 4 matmuls/thread instead of the serial 15 of the old LDS version.
__global__ __launch_bounds__(256) void poly_kernel(const float* __restrict__ Ure,
                                                   const float* __restrict__ Uim,
                                                   u32* __restrict__ T2) {
    int lane = threadIdx.x & 63;
    int c    = lane & 15;                 // start position along mu
    int l    = lane >> 4;                 // 0..3 line-within-wave
    int wv   = threadIdx.x >> 6;          // 0..3
    int lineG = blockIdx.x * 16 + wv * 4 + l;   // mu uniform per block (16|8192)
    int mu   = lineG / NLINE_PER_DIR;
    int lidx = lineG - mu * NLINE_PER_DIR;
    int sh   = 12 - 4 * mu;
    int low  = lidx & ((1 << sh) - 1);
    int high = lidx >> sh;
    int site = (high << (sh + 4)) | (c << sh) | low;
    long base = ((long)site * 4 + mu) * 9;

    M3 P;
#pragma unroll
    for (int e = 0; e < 9; e++) { P.re[e] = Ure[base + e]; P.im[e] = Uim[base + e]; }

#pragma unroll
    for (int k = 1; k < 16; k <<= 1) {
        int src = (lane & 48) | ((c + k) & 15);
        M3 Q, T;
#pragma unroll
        for (int e = 0; e < 9; e++) {
            Q.re[e] = __shfl(P.re[e], src);
            Q.im[e] = __shfl(P.im[e], src);
        }
        mulM(T, P, Q);
        P = T;
    }

    u32* Tp = T2 + base;   // T2 layout [site][mu][e], same base as U link
#pragma unroll
    for (int e = 0; e < 9; e++) Tp[e] = packbf(P.re[e], P.im[e]);
}

// ------- Kernel 2: plaquettes + merge-poly -> W planes -----------------------
// W layout: 27 planes of NSITE uint4. Plane p=(e*3+q); uint4 = j-slots 4q..4q+3
// (j=10,11 zero). LDS: sU (37.9 KB) unioned with sw (13.8 KB, time-disjoint).
// T2 gather hoisted to registers at kernel top (contiguous s0*36+it loads),
// written into sw after the second barrier -> latency overlapped with
// staging + plaquette compute.
__global__ __launch_bounds__(192) void plaq_merge_kernel(const float* __restrict__ Ure,
                                                         const float* __restrict__ Uim,
                                                         const u32* __restrict__ T2,
                                                         u32* __restrict__ W) {
    __shared__ __align__(16) char smem[4 * 32 * 37 * sizeof(float2)];   // 37,888 B
    float2* sU = (float2*)smem;      // live: stage .. P compute
    u32*    sw = (u32*)smem;         // live: after barrier .. W4 write (13,824 B)

    int s0 = blockIdx.x * 32;

    // early T2 prefetch: (s0+ls2)*36 + r == s0*36 + it -> coalesced
    u32 tpre[6]; int tofs[6];
#pragma unroll
    for (int w = 0; w < 6; w++) {
        int it = threadIdx.x + w * 192;
        tpre[w] = T2[(long)s0 * 36 + it];
        int ls2 = it / 36;
        int r   = it - ls2 * 36;
        int mu2 = r / 9;
        int e2  = r - mu2 * 9;
        tofs[w] = ls2 * WSTRIDE + e2 * 12 + 6 + mu2;
    }

    for (int n = threadIdx.x; n < 8 * 16 * 36; n += 192) {
        int run = n / 576;
        int q   = n - run * 576;
        int sir = q / 36;
        int e36 = q - sir * 36;
        int slot = run >> 1, r = run & 1;
        int base = s0 + r * 16;
        if (slot < 3) base = shift_site(base, slot, 1);
        long g = (long)(base + sir) * 36 + e36;
        sU[(slot * 32 + r * 16 + sir) * 37 + e36] = make_float2(Ure[g], Uim[g]);
    }
    __syncthreads();

    int p  = threadIdx.x >> 5;
    int ls = threadIdx.x & 31;

    int mu = (p < 3) ? 0 : ((p < 5) ? 1 : 2);
    int nu = (mu == 0) ? (p + 1) : ((mu == 1) ? (p - 1) : 3);

    M3 Umu, Unu, Unu_f, Umu_f, T1, T2m, P;
    {
        const float2* pp;
#define LDM(m, slot, site, link) \
        pp = &sU[((slot) * 32 + (site)) * 37 + (link) * 9]; \
        _Pragma("unroll") \
        for (int e = 0; e < 9; e++) { float2 v = pp[e]; (m).re[e] = v.x; (m).im[e] = v.y; }

        LDM(Umu, 3, ls, mu);
        LDM(Unu, 3, ls, nu);
        LDM(Unu_f, mu, ls, nu);
        int lsrot = (ls & 16) | ((ls + 1) & 15);
        int fslot = (nu == 3) ? 3 : nu;
        int fsite = (nu == 3) ? lsrot : ls;
        LDM(Umu_f, fslot, fsite, mu);
#undef LDM
    }

    mulM(T1, Umu, Unu_f);
    mulAdjM(T2m, T1, Umu_f);
    mulAdjM(P, T2m, Unu);

    __syncthreads();   // all sU reads done; reuse LDS as sw

#pragma unroll
    for (int e = 0; e < 9; e++) sw[ls * WSTRIDE + e * 12 + p] = packbf(P.re[e], P.im[e]);

    for (int it = threadIdx.x; it < 32 * 9 * 2; it += 192) {
        int site = it / 18;
        int r    = it - site * 18;
        sw[site * WSTRIDE + (r >> 1) * 12 + 10 + (r & 1)] = 0u;
    }

#pragma unroll
    for (int w = 0; w < 6; w++) sw[tofs[w]] = tpre[w];
    __syncthreads();

    uint4* W4 = (uint4*)W;
    for (int it = threadIdx.x; it < 27 * 32; it += 192) {
        int pl  = it >> 5;
        int ls2 = it & 31;
        int e   = pl / 3, q = pl - e * 3;
        const uint4 v = *(const uint4*)(sw + ls2 * WSTRIDE + e * 12 + q * 4);
        W4[(long)pl * NSITE + s0 + ls2] = v;
    }
}

// ---------------- Kernel 3: MFMA gauge-equivariant conv ----------------------
// One wave per 16-site t-line. mfma_f32_16x16x32_bf16 per (mu,kk,e):
//   A[M=16 t-rows][K=32]: k=2j -> W_re[nb][e][j], k=2j+1 -> W_im. Lane l
//     (row=l&15, quad q=l>>4) holds k=q*8..q*8+7 = j-quad q -> ONE uint4 load
//     from plane e*3+q (q==3 -> zero frag; j>=10 already zero-padded in W).
//   B[K=32][N=16]: cols 0-7 Re-out (w_re,-w_im), cols 8-15 Im-out (w_im,w_re);
//     per-lane fragments precomputed into LDS (uint4 per (mk,lane)).
//   D (verified layout): lane holds col c=l&15 (channel-part), rows q*4+[0..3]
//     (t-sites). Epilogue per mu: shfl_xor(8) pairs re<->im lanes; lo lane
//     sandwiches sites q*4+{0,1}, hi lane q*4+{2,3}.
// NOTE: never cap VGPRs via launch_bounds min-waves (round 1: 17x slower).
template <int MODE>
__global__ __launch_bounds__(256) void conv_kernel(const float* __restrict__ Ure,
                                                   const float* __restrict__ Uim,
                                                   const u32* __restrict__ W,
                                                   const float* __restrict__ omre,
                                                   const float* __restrict__ omim,
                                                   float* __restrict__ out) {
    __shared__ __align__(16) char smraw[64 * 72 * sizeof(float)];   // 18,432 B
    uint4* somB = (uint4*)smraw;   // [mk*64+lane], 12,288 B, live during loop
    float* sout = (float*)smraw;   // 18,432 B, live after loop (MODE 2)

    // B-fragment precompute: lane (c=lane&15, q=lane>>4); word w -> j=q*4+w
    for (int n = threadIdx.x; n < 12 * 64; n += 256) {
        int mk = n >> 6, ln = n & 63;
        int q = ln >> 4, c = ln & 15, i = c & 7;
        int mu = mk / 3, kk = mk - mu * 3;
        u32 wv[4];
#pragma unroll
        for (int w = 0; w < 4; w++) {
            int j = q * 4 + w;
            u32 val = 0u;
            if (q < 3 && j < NIN) {
                int oidx = ((i * NIN + j) * ND + mu) * 3 + kk;
                float orv = omre[oidx], oiv = omim[oidx];
                val = (c < 8) ? packbf(orv, -oiv) : packbf(oiv, orv);
            }
            wv[w] = val;
        }
        somB[n] = make_uint4(wv[0], wv[1], wv[2], wv[3]);
    }
    __syncthreads();

    // XCD-aware bijective swizzle (gridDim.x = 2048, divisible by 8)
    int chunk = gridDim.x >> 3;
    int lb    = ((int)blockIdx.x & 7) * chunk + ((int)blockIdx.x >> 3);

    int lane = threadIdx.x & 63;
    int wv_  = threadIdx.x >> 6;          // 0..3
    int r    = lane & 15;                 // A-row (t) / D-col (channel-part)
    int q    = lane >> 4;                 // k-quad / D-row block
    int s0b  = lb * 64;
    int sline = s0b + wv_ * 16;

    const uint4* W4 = (const uint4*)W;

    bool hi = (r >= 8);
    int  i  = r & 7;                      // output channel for epilogue
    int  reg0 = hi ? 2 : 0;               // D-rows handled by this lane

    float accr[2][9], acci[2][9];
#pragma unroll
    for (int rr = 0; rr < 2; rr++)
#pragma unroll
        for (int e = 0; e < 9; e++) { accr[rr][e] = 0.f; acci[rr][e] = 0.f; }

    for (int mu = 0; mu < ND; mu++) {
        f32x4 acc[9];
#pragma unroll
        for (int e = 0; e < 9; e++) acc[e] = (f32x4)(0.f);

        for (int kk = 0; kk < 3; kk++) {
            int mk = mu * 3 + kk;
            s16x8 bfrag = as_s16x8(somB[mk * 64 + lane]);

            int nb;
            if (mu < 3) nb = shift_site(sline, mu, kk - 1) + r;
            else        nb = sline + ((r + kk - 1) & 15);

            uint4 w9[9];
            if (q < 3) {
#pragma unroll
                for (int e = 0; e < 9; e++) w9[e] = W4[(long)(e * 3 + q) * NSITE + nb];
            } else {
#pragma unroll
                for (int e = 0; e < 9; e++) w9[e] = make_uint4(0u, 0u, 0u, 0u);
            }
#pragma unroll
            for (int e = 0; e < 9; e++)
                acc[e] = __builtin_amdgcn_mfma_f32_16x16x32_bf16(as_s16x8(w9[e]), bfrag, acc[e], 0, 0, 0);
        }

        // exchange: partner holds the other complex part of M for my 2 rows
        float own[2][9], oth[2][9];
#pragma unroll
        for (int e = 0; e < 9; e++) {
            float t0 = __shfl_xor(acc[e][0], 8);
            float t1 = __shfl_xor(acc[e][1], 8);
            float t2 = __shfl_xor(acc[e][2], 8);
            float t3 = __shfl_xor(acc[e][3], 8);
            own[0][e] = hi ? acc[e][2] : acc[e][0];
            own[1][e] = hi ? acc[e][3] : acc[e][1];
            oth[0][e] = hi ? t2 : t0;
            oth[1][e] = hi ? t3 : t1;
        }

        // sandwich A * M * A^H for this lane's 2 sites
#pragma unroll
        for (int rr = 0; rr < 2; rr++) {
            int site = sline + q * 4 + reg0 + rr;
            M3 A, M;
            {
                const float* pr = Ure + ((long)site * 4 + mu) * 9;
                const float* pi = Uim + ((long)site * 4 + mu) * 9;
#pragma unroll
                for (int e = 0; e < 9; e++) { A.re[e] = pr[e]; A.im[e] = pi[e]; }
            }
#pragma unroll
            for (int e = 0; e < 9; e++) {
                M.re[e] = hi ? oth[rr][e] : own[rr][e];
                M.im[e] = hi ? own[rr][e] : oth[rr][e];
            }
            M3 Tm;
#pragma unroll
            for (int rw = 0; rw < 3; rw++) {
#pragma unroll
                for (int cl = 0; cl < 3; cl++) {
                    float xr = 0.f, xi = 0.f;
#pragma unroll
                    for (int k = 0; k < 3; k++) {
                        float ar = A.re[rw*3+k], ai = A.im[rw*3+k];
                        float br = M.re[k*3+cl], bi = M.im[k*3+cl];
                        xr = fmaf(ar, br, xr); xr = fmaf(-ai, bi, xr);
                        xi = fmaf(ar, bi, xi); xi = fmaf(ai, br, xi);
                    }
                    Tm.re[rw*3+cl] = xr; Tm.im[rw*3+cl] = xi;
                }
            }
#pragma unroll
            for (int rw = 0; rw < 3; rw++) {
#pragma unroll
                for (int cl = 0; cl < 3; cl++) {
                    float xr = 0.f, xi = 0.f;
#pragma unroll
                    for (int k = 0; k < 3; k++) {
                        float ar = Tm.re[rw*3+k], ai = Tm.im[rw*3+k];
                        float br = A.re[cl*3+k], bi = A.im[cl*3+k];
                        xr = fmaf(ar, br, xr); xr = fmaf(ai, bi, xr);
                        if (MODE != 2) { xi = fmaf(ai, br, xi); xi = fmaf(-ar, bi, xi); }
                    }
                    accr[rr][rw*3+cl] += xr;
                    if (MODE != 2) acci[rr][rw*3+cl] += xi;
                }
            }
        }
    }

    if (MODE == 2) {
        __syncthreads();   // all somB reads done before aliasing as sout
#pragma unroll
        for (int rr = 0; rr < 2; rr++) {
            int tloc = wv_ * 16 + q * 4 + reg0 + rr;
#pragma unroll
            for (int e = 0; e < 9; e++)
                sout[(tloc * 8 + i) * 9 + e] = accr[rr][e];
        }
        __syncthreads();
        long base = (long)lb * 4608;
        for (int n = threadIdx.x; n < 4608; n += 256) out[base + n] = sout[n];
    } else if (MODE == 0) {
#pragma unroll
        for (int rr = 0; rr < 2; rr++) {
            int site = sline + q * 4 + reg0 + rr;
            long cb = ((long)site * 8 + i) * 9;
            float2* op = (float2*)(out + cb * 2);
#pragma unroll
            for (int e = 0; e < 9; e++) op[e] = make_float2(accr[rr][e], acci[rr][e]);
        }
    } else {
#pragma unroll
        for (int rr = 0; rr < 2; rr++) {
            int site = sline + q * 4 + reg0 + rr;
            long cb = ((long)site * 8 + i) * 9;
#pragma unroll
            for (int e = 0; e < 9; e++) {
                out[cb + e]         = accr[rr][e];
                out[NCPLX + cb + e] = acci[rr][e];
            }
        }
    }
}

extern "C" void kernel_launch(void* const* d_in, const int* in_sizes, int n_in,
                              void* d_out, int out_size, void* d_ws, size_t ws_size,
                              hipStream_t stream) {
    const float* Ure  = (const float*)d_in[0];
    const float* Uim  = (const float*)d_in[1];
    const float* omre = (const float*)d_in[2];
    const float* omim = (const float*)d_in[3];
    float* out = (float*)d_out;

    const size_t wBytes = (size_t)NSITE * WSTRIDE * sizeof(u32);   // 56.6 MB (27 planes)
    if (ws_size < wBytes) return;

    u32* W  = (u32*)d_ws;
    u32* T2 = (u32*)d_out;   // 18.9 MB temp in d_out; overwritten by conv

    poly_kernel<<<NSITE * 4 / (16 * 16), 256, 0, stream>>>(Ure, Uim, T2);
    plaq_merge_kernel<<<NSITE / 32, 192, 0, stream>>>(Ure, Uim, T2, W);

    const int convGrid = NSITE / 64;   // 2048 blocks, 64 sites each (4 waves)
    if (out_size == (int)NCPLX)
        conv_kernel<2><<<convGrid, 256, 0, stream>>>(Ure, Uim, W, omre, omim, out);
    else if (out_size == (int)(2 * NCPLX))
        conv_kernel<1><<<convGrid, 256, 0, stream>>>(Ure, Uim, W, omre, omim, out);
    else
        conv_kernel<0><<<convGrid, 256, 0, stream>>>(Ure, Uim, W, omre, omim, out);
}

// Round 6
// 220.105 us; speedup vs baseline: 1.4084x; 1.0895x over previous
//
#include <hip/hip_runtime.h>

#define LSZ   16
#define NBATCH 2
#define NSITE (NBATCH*LSZ*LSZ*LSZ*LSZ)   // 131072
#define NIN   10
#define NOUT  8
#define ND    4
#define NCPLX ((long)NSITE * NOUT * 9)   // 9,437,184 complex output elements
#define NLINE_PER_DIR (NSITE / LSZ)      // 8192
#define NLINK (NSITE * ND)               // 524288
#define WSTRIDE 108                      // u32 per site in LDS image: 9 e * 12 ch (10 used)

typedef unsigned int u32;
typedef float  f32x4 __attribute__((ext_vector_type(4)));
typedef short  s16x8 __attribute__((ext_vector_type(8)));

struct M3 { float re[9]; float im[9]; };

// bf16 pack helpers: u32 = bf16(lo) | bf16(hi)<<16
__device__ __forceinline__ unsigned short f2bf(float x) {
    u32 u = __float_as_uint(x);
    u32 r = (u + 0x7fffu + ((u >> 16) & 1u)) >> 16;   // RNE
    return (unsigned short)r;
}
__device__ __forceinline__ u32 packbf(float lo, float hi) {
    return (u32)f2bf(lo) | ((u32)f2bf(hi) << 16);
}

__device__ __forceinline__ s16x8 as_s16x8(uint4 v) {
    union { uint4 u; s16x8 s; } x; x.u = v; return x.s;
}

// o = a * b
__device__ __forceinline__ void mulM(M3& o, const M3& a, const M3& b) {
#pragma unroll
    for (int r = 0; r < 3; r++) {
#pragma unroll
        for (int c = 0; c < 3; c++) {
            float xr = 0.f, xi = 0.f;
#pragma unroll
            for (int k = 0; k < 3; k++) {
                float ar = a.re[r*3+k], ai = a.im[r*3+k];
                float br = b.re[k*3+c], bi = b.im[k*3+c];
                xr = fmaf(ar, br, xr); xr = fmaf(-ai, bi, xr);
                xi = fmaf(ar, bi, xi); xi = fmaf(ai, br, xi);
            }
            o.re[r*3+c] = xr; o.im[r*3+c] = xi;
        }
    }
}

// o = a * b^H
__device__ __forceinline__ void mulAdjM(M3& o, const M3& a, const M3& b) {
#pragma unroll
    for (int r = 0; r < 3; r++) {
#pragma unroll
        for (int c = 0; c < 3; c++) {
            float xr = 0.f, xi = 0.f;
#pragma unroll
            for (int k = 0; k < 3; k++) {
                float ar = a.re[r*3+k], ai = a.im[r*3+k];
                float br = b.re[c*3+k], bi = b.im[c*3+k];
                xr = fmaf(ar, br, xr); xr = fmaf(ai, bi, xr);
                xi = fmaf(ai, br, xi); xi = fmaf(-ar, bi, xi);
            }
            o.re[r*3+c] = xr; o.im[r*3+c] = xi;
        }
    }
}

// site s = b*65536 + x*4096 + y*256 + z*16 + t ; mu: 0->x,1->y,2->z,3->t
__device__ __forceinline__ int shift_site(int s, int mu, int k) {
    int sh = 12 - 4 * mu;
    int c  = (s >> sh) & 15;
    int nc = (c + k) & 15;
    return (s & ~(15 << sh)) | (nc << sh);
}

// ---------------- Kernel 1: Polyakov -> site-major T2 ------------------------
// v3 = coalesced LDS staging (round-4 pattern: contiguous ~1KB windows per
// wave, TLB-friendly) + parallel doubling scan (round-5: 4 matmuls/thread via
// intra-wave __shfl). Round-5's direct per-lane loads were scattered at
// (1<<sh)*144B lane stride (576 KB for mu=x) -> TLB/L1-tag pathology.
__global__ __launch_bounds__(256) void poly_kernel(const float* __restrict__ Ure,
                                                   const float* __restrict__ Uim,
                                                   u32* __restrict__ T2) {
    __shared__ float2 sm[16 * 145];   // 18.56 KB

    int line0 = blockIdx.x * 16;
    int mu    = line0 / NLINE_PER_DIR;
    int lidx0 = line0 - mu * NLINE_PER_DIR;
    int sh    = 12 - 4 * mu;
    int low0  = lidx0 & ((1 << sh) - 1);
    int high0 = lidx0 >> sh;
    int s_base0 = (high0 << (sh + 4)) | low0;

    for (int n = threadIdx.x; n < 16 * 16 * 9; n += 256) {
        int siteIdx = n / 9;
        int e       = n - siteIdx * 9;
        int site, l, c;
        if (mu == 3) { site = (lidx0 << 4) + siteIdx; l = siteIdx >> 4; c = siteIdx & 15; }
        else         { site = s_base0 + ((siteIdx >> 4) << sh) + (siteIdx & 15);
                       l = siteIdx & 15; c = siteIdx >> 4; }
        long g = ((long)site * 4 + mu) * 9 + e;
        sm[l * 145 + c * 9 + e] = make_float2(Ure[g], Uim[g]);
    }
    __syncthreads();

    int lane = threadIdx.x & 63;
    int c    = threadIdx.x & 15;
    int l    = threadIdx.x >> 4;

    M3 P;
    {
        const float2* m0 = &sm[l * 145 + c * 9];
#pragma unroll
        for (int e = 0; e < 9; e++) { float2 v = m0[e]; P.re[e] = v.x; P.im[e] = v.y; }
    }

    // doubling scan: M2(c)=U_c*U_{c+1}; M4=M2*M2(+2); M8; M16 = P_c (mod 16).
    // 16 positions of a line live in one 16-lane group -> pure shfl.
#pragma unroll
    for (int k = 1; k < 16; k <<= 1) {
        int src = (lane & 48) | ((c + k) & 15);
        M3 Q, T;
#pragma unroll
        for (int e = 0; e < 9; e++) {
            Q.re[e] = __shfl(P.re[e], src);
            Q.im[e] = __shfl(P.im[e], src);
        }
        mulM(T, P, Q);
        P = T;
    }

    // site for (line=lidx0+l, start pos c)
    int lidx = lidx0 + l;
    int low  = lidx & ((1 << sh) - 1);
    int high = lidx >> sh;
    int site = (high << (sh + 4)) | (c << sh) | low;
    u32* Tp = T2 + ((long)site * 4 + mu) * 9;
#pragma unroll
    for (int e = 0; e < 9; e++) Tp[e] = packbf(P.re[e], P.im[e]);
}

// ------- Kernel 2: plaquettes + merge-poly -> W planes -----------------------
// Direct-load version: no sU staging, no stage barrier. Each plane-thread
// loads its 4 matrices straight from global (72 dwords, full ILP); intra-block
// link reuse is L1-served (~23KB working set/wave < 32KB L1). LDS = sw only
// (13.8 KB) -> occupancy 12 -> ~16-20 waves/CU. One barrier total.
// W layout: 27 planes of NSITE uint4; plane p=(e*3+q); uint4 = j-slots 4q..4q+3.
__global__ __launch_bounds__(192) void plaq_merge_kernel(const float* __restrict__ Ure,
                                                         const float* __restrict__ Uim,
                                                         const u32* __restrict__ T2,
                                                         u32* __restrict__ W) {
    __shared__ u32 sw[32 * WSTRIDE];     // 13,824 B

    int s0 = blockIdx.x * 32;

    // early T2 prefetch: coalesced s0*36 + it
    u32 tpre[6]; int tofs[6];
#pragma unroll
    for (int w = 0; w < 6; w++) {
        int it = threadIdx.x + w * 192;
        tpre[w] = T2[(long)s0 * 36 + it];
        int ls2 = it / 36;
        int r   = it - ls2 * 36;
        int mu2 = r / 9;
        int e2  = r - mu2 * 9;
        tofs[w] = ls2 * WSTRIDE + e2 * 12 + 6 + mu2;
    }

    int p  = threadIdx.x >> 5;
    int ls = threadIdx.x & 31;
    int s  = s0 + ls;

    int mu = (p < 3) ? 0 : ((p < 5) ? 1 : 2);
    int nu = (mu == 0) ? (p + 1) : ((mu == 1) ? (p - 1) : 3);

    M3 Umu, Unu, Unu_f, Umu_f, T1, T2m, P;
#define LDG(m, site, link) { \
        long base_ = ((long)(site) * 4 + (link)) * 9; \
        _Pragma("unroll") \
        for (int e = 0; e < 9; e++) { (m).re[e] = Ure[base_ + e]; (m).im[e] = Uim[base_ + e]; } }

    LDG(Umu,   s,                      mu);
    LDG(Unu,   s,                      nu);
    LDG(Unu_f, shift_site(s, mu, 1),   nu);
    LDG(Umu_f, shift_site(s, nu, 1),   mu);
#undef LDG

    mulM(T1, Umu, Unu_f);
    mulAdjM(T2m, T1, Umu_f);
    mulAdjM(P, T2m, Unu);

#pragma unroll
    for (int e = 0; e < 9; e++) sw[ls * WSTRIDE + e * 12 + p] = packbf(P.re[e], P.im[e]);

    // pad j-slots 10,11 zeroed
    for (int it = threadIdx.x; it < 32 * 9 * 2; it += 192) {
        int site = it / 18;
        int r    = it - site * 18;
        sw[site * WSTRIDE + (r >> 1) * 12 + 10 + (r & 1)] = 0u;
    }

    // T2 merge (j-slots 6..9)
#pragma unroll
    for (int w = 0; w < 6; w++) sw[tofs[w]] = tpre[w];
    __syncthreads();

    // plane-transposed write: 27 planes x 32 consecutive uint4
    uint4* W4 = (uint4*)W;
    for (int it = threadIdx.x; it < 27 * 32; it += 192) {
        int pl  = it >> 5;
        int ls2 = it & 31;
        int e   = pl / 3, q = pl - e * 3;
        const uint4 v = *(const uint4*)(sw + ls2 * WSTRIDE + e * 12 + q * 4);
        W4[(long)pl * NSITE + s0 + ls2] = v;
    }
}

// ---------------- Kernel 3: MFMA gauge-equivariant conv ----------------------
// One wave per 16-site t-line. mfma_f32_16x16x32_bf16 per (mu,kk,e):
//   A[M=16 t-rows][K=32]: k=2j -> W_re[nb][e][j], k=2j+1 -> W_im. Lane l
//     (row=l&15, quad q=l>>4) holds k=q*8..q*8+7 = j-quad q -> ONE uint4 load
//     from plane e*3+q (q==3 -> zero frag; j>=10 already zero-padded in W).
//   B[K=32][N=16]: cols 0-7 Re-out (w_re,-w_im), cols 8-15 Im-out (w_im,w_re);
//     per-lane fragments precomputed into LDS (uint4 per (mk,lane)).
//   D: lane holds col c=l&15, rows q*4+[0..3] (t-sites). Epilogue per mu:
//     shfl_xor(8) pairs re<->im lanes; sandwich A*M*A^H on 2 sites/lane.
// NOTE: never cap VGPRs via launch_bounds min-waves (round 1: 17x slower).
template <int MODE>
__global__ __launch_bounds__(256) void conv_kernel(const float* __restrict__ Ure,
                                                   const float* __restrict__ Uim,
                                                   const u32* __restrict__ W,
                                                   const float* __restrict__ omre,
                                                   const float* __restrict__ omim,
                                                   float* __restrict__ out) {
    __shared__ __align__(16) char smraw[64 * 72 * sizeof(float)];   // 18,432 B
    uint4* somB = (uint4*)smraw;   // [mk*64+lane], 12,288 B, live during loop
    float* sout = (float*)smraw;   // 18,432 B, live after loop (MODE 2)

    // B-fragment precompute: lane (c=lane&15, q=lane>>4); word w -> j=q*4+w
    for (int n = threadIdx.x; n < 12 * 64; n += 256) {
        int mk = n >> 6, ln = n & 63;
        int q = ln >> 4, c = ln & 15, i = c & 7;
        int mu = mk / 3, kk = mk - mu * 3;
        u32 wv[4];
#pragma unroll
        for (int w = 0; w < 4; w++) {
            int j = q * 4 + w;
            u32 val = 0u;
            if (q < 3 && j < NIN) {
                int oidx = ((i * NIN + j) * ND + mu) * 3 + kk;
                float orv = omre[oidx], oiv = omim[oidx];
                val = (c < 8) ? packbf(orv, -oiv) : packbf(oiv, orv);
            }
            wv[w] = val;
        }
        somB[n] = make_uint4(wv[0], wv[1], wv[2], wv[3]);
    }
    __syncthreads();

    // XCD-aware bijective swizzle (gridDim.x = 2048, divisible by 8)
    int chunk = gridDim.x >> 3;
    int lb    = ((int)blockIdx.x & 7) * chunk + ((int)blockIdx.x >> 3);

    int lane = threadIdx.x & 63;
    int wv_  = threadIdx.x >> 6;          // 0..3
    int r    = lane & 15;                 // A-row (t) / D-col (channel-part)
    int q    = lane >> 4;                 // k-quad / D-row block
    int s0b  = lb * 64;
    int sline = s0b + wv_ * 16;

    const uint4* W4 = (const uint4*)W;

    bool hi = (r >= 8);
    int  i  = r & 7;                      // output channel for epilogue
    int  reg0 = hi ? 2 : 0;               // D-rows handled by this lane

    float accr[2][9], acci[2][9];
#pragma unroll
    for (int rr = 0; rr < 2; rr++)
#pragma unroll
        for (int e = 0; e < 9; e++) { accr[rr][e] = 0.f; acci[rr][e] = 0.f; }

    for (int mu = 0; mu < ND; mu++) {
        f32x4 acc[9];
#pragma unroll
        for (int e = 0; e < 9; e++) acc[e] = (f32x4)(0.f);

        for (int kk = 0; kk < 3; kk++) {
            int mk = mu * 3 + kk;
            s16x8 bfrag = as_s16x8(somB[mk * 64 + lane]);

            int nb;
            if (mu < 3) nb = shift_site(sline, mu, kk - 1) + r;
            else        nb = sline + ((r + kk - 1) & 15);

            uint4 w9[9];
            if (q < 3) {
#pragma unroll
                for (int e = 0; e < 9; e++) w9[e] = W4[(long)(e * 3 + q) * NSITE + nb];
            } else {
#pragma unroll
                for (int e = 0; e < 9; e++) w9[e] = make_uint4(0u, 0u, 0u, 0u);
            }
#pragma unroll
            for (int e = 0; e < 9; e++)
                acc[e] = __builtin_amdgcn_mfma_f32_16x16x32_bf16(as_s16x8(w9[e]), bfrag, acc[e], 0, 0, 0);
        }

        // exchange: partner holds the other complex part of M for my 2 rows
        float own[2][9], oth[2][9];
#pragma unroll
        for (int e = 0; e < 9; e++) {
            float t0 = __shfl_xor(acc[e][0], 8);
            float t1 = __shfl_xor(acc[e][1], 8);
            float t2 = __shfl_xor(acc[e][2], 8);
            float t3 = __shfl_xor(acc[e][3], 8);
            own[0][e] = hi ? acc[e][2] : acc[e][0];
            own[1][e] = hi ? acc[e][3] : acc[e][1];
            oth[0][e] = hi ? t2 : t0;
            oth[1][e] = hi ? t3 : t1;
        }

        // sandwich A * M * A^H for this lane's 2 sites
#pragma unroll
        for (int rr = 0; rr < 2; rr++) {
            int site = sline + q * 4 + reg0 + rr;
            M3 A, M;
            {
                const float* pr = Ure + ((long)site * 4 + mu) * 9;
                const float* pi = Uim + ((long)site * 4 + mu) * 9;
#pragma unroll
                for (int e = 0; e < 9; e++) { A.re[e] = pr[e]; A.im[e] = pi[e]; }
            }
#pragma unroll
            for (int e = 0; e < 9; e++) {
                M.re[e] = hi ? oth[rr][e] : own[rr][e];
                M.im[e] = hi ? own[rr][e] : oth[rr][e];
            }
            M3 Tm;
#pragma unroll
            for (int rw = 0; rw < 3; rw++) {
#pragma unroll
                for (int cl = 0; cl < 3; cl++) {
                    float xr = 0.f, xi = 0.f;
#pragma unroll
                    for (int k = 0; k < 3; k++) {
                        float ar = A.re[rw*3+k], ai = A.im[rw*3+k];
                        float br = M.re[k*3+cl], bi = M.im[k*3+cl];
                        xr = fmaf(ar, br, xr); xr = fmaf(-ai, bi, xr);
                        xi = fmaf(ar, bi, xi); xi = fmaf(ai, br, xi);
                    }
                    Tm.re[rw*3+cl] = xr; Tm.im[rw*3+cl] = xi;
                }
            }
#pragma unroll
            for (int rw = 0; rw < 3; rw++) {
#pragma unroll
                for (int cl = 0; cl < 3; cl++) {
                    float xr = 0.f, xi = 0.f;
#pragma unroll
                    for (int k = 0; k < 3; k++) {
                        float ar = Tm.re[rw*3+k], ai = Tm.im[rw*3+k];
                        float br = A.re[cl*3+k], bi = A.im[cl*3+k];
                        xr = fmaf(ar, br, xr); xr = fmaf(ai, bi, xr);
                        if (MODE != 2) { xi = fmaf(ai, br, xi); xi = fmaf(-ar, bi, xi); }
                    }
                    accr[rr][rw*3+cl] += xr;
                    if (MODE != 2) acci[rr][rw*3+cl] += xi;
                }
            }
        }
    }

    if (MODE == 2) {
        __syncthreads();   // all somB reads done before aliasing as sout
#pragma unroll
        for (int rr = 0; rr < 2; rr++) {
            int tloc = wv_ * 16 + q * 4 + reg0 + rr;
#pragma unroll
            for (int e = 0; e < 9; e++)
                sout[(tloc * 8 + i) * 9 + e] = accr[rr][e];
        }
        __syncthreads();
        long base = (long)lb * 4608;
        for (int n = threadIdx.x; n < 4608; n += 256) out[base + n] = sout[n];
    } else if (MODE == 0) {
#pragma unroll
        for (int rr = 0; rr < 2; rr++) {
            int site = sline + q * 4 + reg0 + rr;
            long cb = ((long)site * 8 + i) * 9;
            float2* op = (float2*)(out + cb * 2);
#pragma unroll
            for (int e = 0; e < 9; e++) op[e] = make_float2(accr[rr][e], acci[rr][e]);
        }
    } else {
#pragma unroll
        for (int rr = 0; rr < 2; rr++) {
            int site = sline + q * 4 + reg0 + rr;
            long cb = ((long)site * 8 + i) * 9;
#pragma unroll
            for (int e = 0; e < 9; e++) {
                out[cb + e]         = accr[rr][e];
                out[NCPLX + cb + e] = acci[rr][e];
            }
        }
    }
}

extern "C" void kernel_launch(void* const* d_in, const int* in_sizes, int n_in,
                              void* d_out, int out_size, void* d_ws, size_t ws_size,
                              hipStream_t stream) {
    const float* Ure  = (const float*)d_in[0];
    const float* Uim  = (const float*)d_in[1];
    const float* omre = (const float*)d_in[2];
    const float* omim = (const float*)d_in[3];
    float* out = (float*)d_out;

    const size_t wBytes = (size_t)NSITE * WSTRIDE * sizeof(u32);   // 56.6 MB (27 planes)
    if (ws_size < wBytes) return;

    u32* W  = (u32*)d_ws;
    u32* T2 = (u32*)d_out;   // 18.9 MB temp in d_out; overwritten by conv

    poly_kernel<<<NSITE * 4 / (16 * 16), 256, 0, stream>>>(Ure, Uim, T2);
    plaq_merge_kernel<<<NSITE / 32, 192, 0, stream>>>(Ure, Uim, T2, W);

    const int convGrid = NSITE / 64;   // 2048 blocks, 64 sites each (4 waves)
    if (out_size == (int)NCPLX)
        conv_kernel<2><<<convGrid, 256, 0, stream>>>(Ure, Uim, W, omre, omim, out);
    else if (out_size == (int)(2 * NCPLX))
        conv_kernel<1><<<convGrid, 256, 0, stream>>>(Ure, Uim, W, omre, omim, out);
    else
        conv_kernel<0><<<convGrid, 256, 0, stream>>>(Ure, Uim, W, omre, omim, out);
}